// Round 1
// 1126.376 us; speedup vs baseline: 2.6567x; 2.6567x over previous
//
#include <hip/hip_runtime.h>
#include <math.h>

// ---------------------------------------------------------------------------
// MFMA round. fp32 outputs (validated r6). Per-array dtype detection
// (bf16/fp32/zero). All three MLPs: split-bf16 MFMA (hi/lo planes, 3 terms,
// ~1e-6 abs accuracy). Top-8 correctness vs fp64 reference guaranteed by a
// margin-gated fp64 rescue pass (rows with 8th/9th gap < 1e-4 recomputed).
// This round: rescue_kernel rewritten — 16 rows/block batched in LDS,
// branch-free templated weight loads (was latency-bound at ~2033 us).
// ---------------------------------------------------------------------------

typedef __bf16 bf16x8  __attribute__((ext_vector_type(8)));
typedef float  floatx4 __attribute__((ext_vector_type(4)));
#define MFMA(a,b,c) __builtin_amdgcn_mfma_f32_16x16x32_bf16((a),(b),(c),0,0,0)

#define BN 65536
#define IST 136     // input-plane LDS stride (128 + 8)
#define HSTR 520    // hidden-plane LDS stride (512 + 8) -> 2-way bank alias only
#define MARGIN 1e-4f

// packed plane sizes/offsets (bf16 elements); hi at OFF, lo at OFF+SZ
#define SZ_W1 65536
#define SZ_W2 262144
#define SZ_WD 32768
#define SZ_ATT 16384
#define OFF_SW1 0
#define OFF_SW2 (OFF_SW1 + 2*SZ_W1)
#define OFF_SWD (OFF_SW2 + 2*SZ_W2)
#define OFF_MW1 (OFF_SWD + 2*SZ_WD)
#define OFF_MW2 (OFF_MW1 + 2*SZ_W1)
#define OFF_MWD (OFF_MW2 + 2*SZ_W2)
#define OFF_FW1 (OFF_MWD + 2*SZ_WD)
#define OFF_FW2 (OFF_FW1 + 2*SZ_W1)
#define OFF_FWD (OFF_FW2 + 2*SZ_W2)
#define OFF_ATT (OFF_FWD + 2*SZ_WD)

// ws byte offsets (pack ends at ~4.4 MB)
#define WS_MASKS (5u << 20)     // BN * 8 B
#define WS_RROWS (6u << 20)     // up to BN ints
#define WS_RCNT  (7u << 20)     // 1 int
#define WS_FLAGS ((7u << 20) + 256)

enum { R_X = 0, R_Y, R_SW1, R_SB1, R_SW2, R_SB2, R_SWD, R_SBD,
       R_MW1, R_MB1, R_MW2, R_MB2, R_MWD, R_MBD, R_ATTW, R_ATTB,
       R_FW1, R_FB1, R_FW2, R_FB2, R_FWD, R_FBD, N_ROLES };

__device__ __forceinline__ float bf2f(unsigned short u) {
    return __uint_as_float((unsigned)u << 16);
}
// fl: 1=bf16, 0=fp32, 2=zero
__device__ __forceinline__ float loadf(const void* p, size_t i, int fl) {
    return fl == 1 ? bf2f(((const unsigned short*)p)[i])
         : fl == 0 ? ((const float*)p)[i] : 0.f;
}
__device__ __forceinline__ double loadd(const void* p, size_t i, int fl) {
    return fl == 1 ? (double)bf2f(((const unsigned short*)p)[i])
         : fl == 0 ? (double)((const float*)p)[i] : 0.0;
}
// compile-time-flag variant: branch-free loop bodies in the rescue kernel
template<int FL>
__device__ __forceinline__ double ldw(const void* p, size_t i) {
    return FL == 1 ? (double)bf2f(((const unsigned short*)p)[i])
         : FL == 0 ? (double)((const float*)p)[i] : 0.0;
}
struct bf2 { __bf16 hi, lo; };
__device__ __forceinline__ bf2 split2(float v) {
    bf2 r;
    r.hi = (__bf16)v;
    r.lo = (__bf16)(v - (float)r.hi);
    return r;
}

// ---------------------------------------------------------------------------
// detect: per-array dtype (1=bf16, 0=fp32, 2=zero). Also zeroes rescue count.
// ---------------------------------------------------------------------------
struct DetArgs { const void* p[N_ROLES]; int n[N_ROLES]; };

__global__ __launch_bounds__(256) void detect_kernel(DetArgs da, int* flags, int* rcnt) {
    const int role = blockIdx.x;
    if (role == 0 && threadIdx.x == 0) *rcnt = 0;
    const unsigned short* u = (const unsigned short*)da.p[role];
    int nsamp = da.n[role] / 2;
    if (nsamp > 4096) nsamp = 4096;
    __shared__ int band, nz;
    if (threadIdx.x == 0) { band = 0; nz = 0; }
    __syncthreads();
    int lb = 0, lnz = 0;
    for (int i = threadIdx.x; i < nsamp; i += 256) {
        const unsigned short v = u[2 * i];
        if (v) {
            ++lnz;
            const int e = (v >> 7) & 0xFF;
            if (e >= 100 && e <= 126) ++lb;
        }
    }
    atomicAdd(&band, lb);
    atomicAdd(&nz, lnz);
    __syncthreads();
    if (threadIdx.x == 0)
        flags[role] = (nz == 0) ? 2 : ((band * 2 > nz) ? 1 : 0);
}

// ---------------------------------------------------------------------------
// pack: [K x N] -> MFMA B-frag hi/lo planes. Frag for tile (kt,nt): lane l,
// j=0..7 holds W[kt*32 + (l>>4)*8 + j][nt*16 + (l&15)].
// ---------------------------------------------------------------------------
struct PackArgs { const void* src[10]; int K[10], N[10], off[10], role[10]; };

__global__ __launch_bounds__(256) void pack_weights(PackArgs pa, __bf16* dst,
                                                    const int* __restrict__ flags) {
    const int m = blockIdx.y;
    const int fl = flags[pa.role[m]];
    const int K = pa.K[m], N = pa.N[m];
    const int KT = K >> 5, NT = N >> 4;
    const int total = KT * NT * 64;
    const int t = blockIdx.x * 256 + threadIdx.x;
    if (t >= total) return;
    const int l = t & 63;
    const int idx = t >> 6;            // nt*KT + kt
    const int kt = idx % KT;
    const int nt = idx / KT;
    const int k0 = kt * 32 + ((l >> 4) << 3);
    const int n  = nt * 16 + (l & 15);
    __bf16* dh = dst + pa.off[m] + (size_t)t * 8;
    __bf16* dl = dh + K * N;
#pragma unroll
    for (int j = 0; j < 8; ++j) {
        const bf2 s = split2(loadf(pa.src[m], (size_t)(k0 + j) * N + n, fl));
        dh[j] = s.hi;
        dl[j] = s.lo;
    }
}

// ---------------------------------------------------------------------------
// Core 3-layer MFMA MLP (16 rows, 512 threads = 8 waves). Input from ixs
// hi/lo planes; h planes in LDS (in-place L2); fp32 out. SUB also mirrors
// layer-3 output into outb (LDS) for top-k.
// ---------------------------------------------------------------------------
template <bool SUB>
__device__ __forceinline__ void mlp_core(
    const __bf16* __restrict__ ix0, const __bf16* __restrict__ ix1,
    __bf16* __restrict__ h0, __bf16* __restrict__ h1,
    const __bf16* __restrict__ p1h, const __bf16* __restrict__ p1l,
    const __bf16* __restrict__ p2h, const __bf16* __restrict__ p2l,
    const __bf16* __restrict__ pdh, const __bf16* __restrict__ pdl,
    const void* __restrict__ b1, int fb1,
    const void* __restrict__ b2, int fb2,
    const void* __restrict__ bd, int fbd,
    int r0, float* __restrict__ out, float* __restrict__ outb)
{
    const int tid = threadIdx.x;
    const int l = tid & 63, w = tid >> 6, l15 = l & 15, q = l >> 4;

    // ---- layer 1: K=128, wave w owns 64-col slab ----
    floatx4 acc[4];
#pragma unroll
    for (int nt = 0; nt < 4; ++nt) acc[nt] = (floatx4)0.0f;
#pragma unroll
    for (int kt = 0; kt < 4; ++kt) {
        const int ab = l15 * IST + kt * 32 + q * 8;
        const bf16x8 ahi = *(const bf16x8*)&ix0[ab];
        const bf16x8 alo = *(const bf16x8*)&ix1[ab];
#pragma unroll
        for (int nt = 0; nt < 4; ++nt) {
            const size_t fi = ((((size_t)(w * 4 + nt)) * 4 + kt) * 64 + l) * 8;
            const bf16x8 bhi = *(const bf16x8*)(p1h + fi);
            const bf16x8 blo = *(const bf16x8*)(p1l + fi);
            acc[nt] = MFMA(alo, bhi, acc[nt]);
            acc[nt] = MFMA(ahi, blo, acc[nt]);
            acc[nt] = MFMA(ahi, bhi, acc[nt]);
        }
    }
#pragma unroll
    for (int nt = 0; nt < 4; ++nt) {
        const int col = w * 64 + nt * 16 + l15;
        const float bias = loadf(b1, col, fb1);
#pragma unroll
        for (int r = 0; r < 4; ++r) {
            const int rowl = q * 4 + r;
            float v = acc[nt][r] + bias;
            v = v > 0.f ? v : 0.f;
            const bf2 s = split2(v);
            h0[rowl * HSTR + col] = s.hi;
            h1[rowl * HSTR + col] = s.lo;
        }
    }
    __syncthreads();

    // ---- layer 2: K=512, in-place ----
    floatx4 acc2[4];
#pragma unroll
    for (int nt = 0; nt < 4; ++nt) acc2[nt] = (floatx4)0.0f;
    for (int kt = 0; kt < 16; ++kt) {
        const int ab = l15 * HSTR + kt * 32 + q * 8;
        const bf16x8 ahi = *(const bf16x8*)&h0[ab];
        const bf16x8 alo = *(const bf16x8*)&h1[ab];
#pragma unroll
        for (int nt = 0; nt < 4; ++nt) {
            const size_t fi = ((((size_t)(w * 4 + nt)) * 16 + kt) * 64 + l) * 8;
            const bf16x8 bhi = *(const bf16x8*)(p2h + fi);
            const bf16x8 blo = *(const bf16x8*)(p2l + fi);
            acc2[nt] = MFMA(alo, bhi, acc2[nt]);
            acc2[nt] = MFMA(ahi, blo, acc2[nt]);
            acc2[nt] = MFMA(ahi, bhi, acc2[nt]);
        }
    }
    __syncthreads();  // all reads of h done before overwrite
#pragma unroll
    for (int nt = 0; nt < 4; ++nt) {
        const int col = w * 64 + nt * 16 + l15;
        const float bias = loadf(b2, col, fb2);
#pragma unroll
        for (int r = 0; r < 4; ++r) {
            const int rowl = q * 4 + r;
            float v = acc2[nt][r] + bias;
            v = v > 0.f ? v : 0.f;
            const bf2 s = split2(v);
            h0[rowl * HSTR + col] = s.hi;
            h1[rowl * HSTR + col] = s.lo;
        }
    }
    __syncthreads();

    // ---- layer 3: K=512, N=64; waves 0..3 (nt=w) ----
    if (w < 4) {
        floatx4 a3 = (floatx4)0.0f;
        for (int kt = 0; kt < 16; ++kt) {
            const int ab = l15 * HSTR + kt * 32 + q * 8;
            const bf16x8 ahi = *(const bf16x8*)&h0[ab];
            const bf16x8 alo = *(const bf16x8*)&h1[ab];
            const size_t fi = (((size_t)(w * 16 + kt)) * 64 + l) * 8;
            const bf16x8 bhi = *(const bf16x8*)(pdh + fi);
            const bf16x8 blo = *(const bf16x8*)(pdl + fi);
            a3 = MFMA(alo, bhi, a3);
            a3 = MFMA(ahi, blo, a3);
            a3 = MFMA(ahi, bhi, a3);
        }
        const int col = w * 16 + l15;
        const float bias = loadf(bd, col, fbd);
#pragma unroll
        for (int r = 0; r < 4; ++r) {
            const int rowl = q * 4 + r;
            const float v = a3[r] + bias;  // no relu on output layer
            out[(size_t)(r0 + rowl) * 64 + col] = v;
            if (SUB) outb[rowl * 64 + col] = v;
        }
    }
    if (SUB) __syncthreads();
}

// ---------------------------------------------------------------------------
// K1: sub MLP + per-row top-8 mask + margin-gated rescue list.
// ---------------------------------------------------------------------------
__global__ __launch_bounds__(512, 4)
void sub_mfma(const void* __restrict__ x, const __bf16* __restrict__ wpack,
              const void* __restrict__ b1, const void* __restrict__ b2,
              const void* __restrict__ bd, const int* __restrict__ flags,
              float* __restrict__ out, unsigned long long* __restrict__ masks,
              int* __restrict__ rrows, int* __restrict__ rcnt)
{
    __shared__ __align__(16) __bf16 ixs[2][16 * IST];
    __shared__ __align__(16) __bf16 h[2][16 * HSTR];
    __shared__ float outb[16 * 64];
    const int fx = flags[R_X];
    const int r0 = blockIdx.x * 16;

    for (int i = threadIdx.x; i < 2048; i += 512) {
        const int r = i >> 7, c = i & 127;
        const bf2 s = split2(loadf(x, (size_t)(r0 + r) * 128 + c, fx));
        ixs[0][r * IST + c] = s.hi;
        ixs[1][r * IST + c] = s.lo;
    }
    __syncthreads();

    mlp_core<true>(ixs[0], ixs[1], h[0], h[1],
                   wpack + OFF_SW1, wpack + OFF_SW1 + SZ_W1,
                   wpack + OFF_SW2, wpack + OFF_SW2 + SZ_W2,
                   wpack + OFF_SWD, wpack + OFF_SWD + SZ_WD,
                   b1, flags[R_SB1], b2, flags[R_SB2], bd, flags[R_SBD],
                   r0, out, outb);

    // top-9 per row (strict '>' insertion: jax tie rule -> lowest index wins)
    if (threadIdx.x < 16) {
        const float* rowp = &outb[threadIdx.x * 64];
        float vals[9];
        int idxs[9];
#pragma unroll
        for (int j = 0; j < 9; ++j) { vals[j] = -__builtin_inff(); idxs[j] = 0; }
        for (int i = 0; i < 64; ++i) {
            const float v = rowp[i];
            if (v > vals[8]) {
                int p = 8;
                while (p > 0 && v > vals[p - 1]) {
                    vals[p] = vals[p - 1];
                    idxs[p] = idxs[p - 1];
                    --p;
                }
                vals[p] = v;
                idxs[p] = i;
            }
        }
        unsigned long long m = 0ull;
#pragma unroll
        for (int j = 0; j < 8; ++j) m |= (1ull << idxs[j]);
        masks[r0 + threadIdx.x] = m;
        if (vals[7] - vals[8] < MARGIN) {
            const int slot = atomicAdd(rcnt, 1);
            rrows[slot] = r0 + threadIdx.x;
        }
    }
}

// ---------------------------------------------------------------------------
// K1b: fp64 rescue for marginal rows — recompute sub rows exactly, fix mask
// and out_sub rows. Batched: 16 rows per block-iteration staged in LDS so
// each weight element is loaded once and FMA'd into 16 row-accumulators.
// Per-output accumulation order (sequential k, fp64 fma) is identical to the
// previous per-row version -> bitwise-identical results.
// ---------------------------------------------------------------------------
#define RPB 16
#define XST 130    // xs row stride (128 + 2)
#define HST2 516   // h row stride (512 + 4)

// L1/L2: 256 threads own cols (t, t+256); accumulate 16 rows each.
template<int FL, int K, int S>
__device__ __forceinline__ void r_layer12(const void* __restrict__ W,
                                          const double* __restrict__ in,
                                          double* __restrict__ a0,
                                          double* __restrict__ a1, int t)
{
    for (int k = 0; k < K; ++k) {
        const double w0 = ldw<FL>(W, (size_t)k * 512 + t);
        const double w1 = ldw<FL>(W, (size_t)k * 512 + t + 256);
#pragma unroll
        for (int r = 0; r < RPB; ++r) {
            a0[r] = fma(in[r * S + k], w0, a0[r]);
            a1[r] = fma(in[r * S + k], w1, a1[r]);
        }
    }
}

// L3: thread owns col c = t&63, row-group rg = t>>6 (4 rows).
template<int FL>
__device__ __forceinline__ void r_layer3(const void* __restrict__ W,
                                         const double* __restrict__ h,
                                         int c, int rg, double* __restrict__ a)
{
    for (int k = 0; k < 512; ++k) {
        const double w = ldw<FL>(W, (size_t)k * 64 + c);
#pragma unroll
        for (int j = 0; j < 4; ++j)
            a[j] = fma(h[(rg * 4 + j) * HST2 + k], w, a[j]);
    }
}

#define R_DISPATCH(fl, CALL)                                   \
    do {                                                       \
        if ((fl) == 1)      { CALL(1); }                       \
        else if ((fl) == 0) { CALL(0); }                       \
        else                { CALL(2); }                       \
    } while (0)

__global__ __launch_bounds__(256)
void rescue_kernel(const void* __restrict__ x,
                   const void* __restrict__ W1, const void* __restrict__ b1,
                   const void* __restrict__ W2, const void* __restrict__ b2,
                   const void* __restrict__ Wd, const void* __restrict__ bd,
                   const int* __restrict__ flags,
                   const int* __restrict__ rrows, const int* __restrict__ rcnt,
                   float* __restrict__ out, unsigned long long* __restrict__ masks)
{
    __shared__ double xs[RPB * XST];
    __shared__ double h[RPB * HST2];
    __shared__ double ob[RPB][64];
    __shared__ int rowids[RPB];
    const int fx = flags[R_X], f1 = flags[R_SW1], fb1 = flags[R_SB1],
              f2 = flags[R_SW2], fb2 = flags[R_SB2],
              f3 = flags[R_SWD], fb3 = flags[R_SBD];
    const int t = threadIdx.x;
    const int n = *rcnt;

    for (int g = blockIdx.x; g * RPB < n; g += gridDim.x) {
        const int base = g * RPB;
        int cnt = n - base;
        if (cnt > RPB) cnt = RPB;
        if (t < RPB) rowids[t] = rrows[base + (t < cnt ? t : cnt - 1)];
        __syncthreads();

        // stage inputs (fp64)
        for (int i = t; i < RPB * 128; i += 256) {
            const int r = i >> 7, c = i & 127;
            xs[r * XST + c] = loadd(x, (size_t)rowids[r] * 128 + c, fx);
        }
        __syncthreads();

        // ---- L1: K=128 ----
        {
            double a0[RPB], a1[RPB];
#pragma unroll
            for (int r = 0; r < RPB; ++r) { a0[r] = 0.0; a1[r] = 0.0; }
#define L1_CALL(FL) r_layer12<FL, 128, XST>(W1, xs, a0, a1, t)
            R_DISPATCH(f1, L1_CALL);
#undef L1_CALL
            const double bb0 = loadd(b1, t, fb1), bb1 = loadd(b1, t + 256, fb1);
#pragma unroll
            for (int r = 0; r < RPB; ++r) {
                const double v0 = a0[r] + bb0, v1 = a1[r] + bb1;
                h[r * HST2 + t]       = v0 > 0.0 ? v0 : 0.0;
                h[r * HST2 + t + 256] = v1 > 0.0 ? v1 : 0.0;
            }
        }
        __syncthreads();

        // ---- L2: K=512, in-place (accumulate fully, then overwrite) ----
        {
            double a0[RPB], a1[RPB];
#pragma unroll
            for (int r = 0; r < RPB; ++r) { a0[r] = 0.0; a1[r] = 0.0; }
#define L2_CALL(FL) r_layer12<FL, 512, HST2>(W2, h, a0, a1, t)
            R_DISPATCH(f2, L2_CALL);
#undef L2_CALL
            __syncthreads();  // all reads of h done before overwrite
            const double bb0 = loadd(b2, t, fb2), bb1 = loadd(b2, t + 256, fb2);
#pragma unroll
            for (int r = 0; r < RPB; ++r) {
                const double v0 = a0[r] + bb0, v1 = a1[r] + bb1;
                h[r * HST2 + t]       = v0 > 0.0 ? v0 : 0.0;
                h[r * HST2 + t + 256] = v1 > 0.0 ? v1 : 0.0;
            }
        }
        __syncthreads();

        // ---- L3: K=512, N=64; col c, 4 rows per thread ----
        {
            const int c = t & 63, rg = t >> 6;
            double a[4];
#pragma unroll
            for (int j = 0; j < 4; ++j) a[j] = 0.0;
#define L3_CALL(FL) r_layer3<FL>(Wd, h, c, rg, a)
            R_DISPATCH(f3, L3_CALL);
#undef L3_CALL
            const double bb = loadd(bd, c, fb3);
#pragma unroll
            for (int j = 0; j < 4; ++j) {
                const int r = rg * 4 + j;
                const double v = a[j] + bb;
                ob[r][c] = v;
                if (r < cnt) out[(size_t)rowids[r] * 64 + c] = (float)v;
            }
        }
        __syncthreads();

        // ---- top-8 per valid row (strict '>' insertion, as before) ----
        if (t < cnt) {
            double vals[8];
            int idxs[8];
#pragma unroll
            for (int j = 0; j < 8; ++j) { vals[j] = -1.0e300; idxs[j] = 0; }
            for (int i = 0; i < 64; ++i) {
                const double v = ob[t][i];
                if (v > vals[7]) {
                    int p = 7;
                    while (p > 0 && v > vals[p - 1]) {
                        vals[p] = vals[p - 1];
                        idxs[p] = idxs[p - 1];
                        --p;
                    }
                    vals[p] = v;
                    idxs[p] = i;
                }
            }
            unsigned long long m = 0ull;
#pragma unroll
            for (int j = 0; j < 8; ++j) m |= (1ull << idxs[j]);
            masks[rowids[t]] = m;
        }
        __syncthreads();  // ob/rowids/xs reused next iteration
    }
}

// ---------------------------------------------------------------------------
// K2: mm MLP from masked y.
// ---------------------------------------------------------------------------
__global__ __launch_bounds__(512, 4)
void mm_mfma(const unsigned long long* __restrict__ masks,
             const void* __restrict__ y, const __bf16* __restrict__ wpack,
             const void* __restrict__ b1, const void* __restrict__ b2,
             const void* __restrict__ bd, const int* __restrict__ flags,
             float* __restrict__ out)
{
    __shared__ __align__(16) __bf16 ixs[2][16 * IST];
    __shared__ __align__(16) __bf16 h[2][16 * HSTR];
    const int fy = flags[R_Y];
    const int r0 = blockIdx.x * 16;

    for (int i = threadIdx.x; i < 2048; i += 512) {
        const int r = i >> 7, c = i & 127;
        const bool keep = (masks[r0 + r] >> (c >> 1)) & 1ull;
        const float v = keep ? loadf(y, (size_t)(r0 + r) * 128 + c, fy) : 0.f;
        const bf2 s = split2(v);
        ixs[0][r * IST + c] = s.hi;
        ixs[1][r * IST + c] = s.lo;
    }
    __syncthreads();

    mlp_core<false>(ixs[0], ixs[1], h[0], h[1],
                    wpack + OFF_MW1, wpack + OFF_MW1 + SZ_W1,
                    wpack + OFF_MW2, wpack + OFF_MW2 + SZ_W2,
                    wpack + OFF_MWD, wpack + OFF_MWD + SZ_WD,
                    b1, flags[R_MB1], b2, flags[R_MB2], bd, flags[R_MBD],
                    r0, out, nullptr);
}

// ---------------------------------------------------------------------------
// K3: cat (fp32 from d_out) -> sigmoid attention gate -> fusion MLP.
// ---------------------------------------------------------------------------
__global__ __launch_bounds__(512, 4)
void fusion_mfma(const float* __restrict__ subf, const float* __restrict__ mmf,
                 const __bf16* __restrict__ wpack,
                 const void* __restrict__ attb,
                 const void* __restrict__ b1, const void* __restrict__ b2,
                 const void* __restrict__ bd, const int* __restrict__ flags,
                 float* __restrict__ out)
{
    __shared__ __align__(16) __bf16 ixs[2][16 * IST];
    __shared__ __align__(16) __bf16 h[2][16 * HSTR];
    const int tid = threadIdx.x;
    const int l = tid & 63, w = tid >> 6, l15 = l & 15, q = l >> 4;
    const int r0 = blockIdx.x * 16;

    for (int i = tid; i < 2048; i += 512) {
        const int r = i >> 7, c = i & 127;
        const size_t row = (size_t)(r0 + r);
        const float v = (c < 64) ? subf[row * 64 + c] : mmf[row * 64 + (c - 64)];
        const bf2 s = split2(v);
        ixs[0][r * IST + c] = s.hi;
        ixs[1][r * IST + c] = s.lo;
    }
    __syncthreads();

    // attention: N=128, wave w owns 16-col tile nt=w
    floatx4 aacc = (floatx4)0.0f;
    const __bf16* path = wpack + OFF_ATT;
    const __bf16* patl = path + SZ_ATT;
#pragma unroll
    for (int kt = 0; kt < 4; ++kt) {
        const int ab = l15 * IST + kt * 32 + q * 8;
        const bf16x8 ahi = *(const bf16x8*)&ixs[0][ab];
        const bf16x8 alo = *(const bf16x8*)&ixs[1][ab];
        const size_t fi = (((size_t)(w * 4 + kt)) * 64 + l) * 8;
        const bf16x8 bhi = *(const bf16x8*)(path + fi);
        const bf16x8 blo = *(const bf16x8*)(patl + fi);
        aacc = MFMA(alo, bhi, aacc);
        aacc = MFMA(ahi, blo, aacc);
        aacc = MFMA(ahi, bhi, aacc);
    }
    const int col = w * 16 + l15;
    const float ab = loadf(attb, col, flags[R_ATTB]);
    float gated[4];
#pragma unroll
    for (int r = 0; r < 4; ++r) {
        const int rowl = q * 4 + r;
        const float pre = aacc[r] + ab;
        const float s = 1.f / (1.f + expf(-pre));
        const float catv = (float)ixs[0][rowl * IST + col] + (float)ixs[1][rowl * IST + col];
        gated[r] = catv * s;
    }
    __syncthreads();  // all attention reads of ixs done
#pragma unroll
    for (int r = 0; r < 4; ++r) {
        const int rowl = q * 4 + r;
        const bf2 s = split2(gated[r]);
        ixs[0][rowl * IST + col] = s.hi;
        ixs[1][rowl * IST + col] = s.lo;
    }
    __syncthreads();

    mlp_core<false>(ixs[0], ixs[1], h[0], h[1],
                    wpack + OFF_FW1, wpack + OFF_FW1 + SZ_W1,
                    wpack + OFF_FW2, wpack + OFF_FW2 + SZ_W2,
                    wpack + OFF_FWD, wpack + OFF_FWD + SZ_WD,
                    b1, flags[R_FB1], b2, flags[R_FB2], bd, flags[R_FBD],
                    r0, out, nullptr);
}

// ---------------------------------------------------------------------------
extern "C" void kernel_launch(void* const* d_in, const int* in_sizes, int n_in,
                              void* d_out, int out_size, void* d_ws, size_t ws_size,
                              hipStream_t stream)
{
    // ---- resolve input order by size signature (dict order vs sorted) ----
    static const int dictSizes[23] = {8388608, 8388608, 65536, 512, 262144, 512,
                                      32768, 64, 65536, 512, 262144, 512, 32768, 64,
                                      16384, 128, 65536, 512, 262144, 512, 32768, 64, 1};
    static const int dictRole[23]  = {R_X, R_Y, R_SW1, R_SB1, R_SW2, R_SB2, R_SWD, R_SBD,
                                      R_MW1, R_MB1, R_MW2, R_MB2, R_MWD, R_MBD,
                                      R_ATTW, R_ATTB, R_FW1, R_FB1, R_FW2, R_FB2,
                                      R_FWD, R_FBD, -1};
    static const int sortSizes[23] = {128, 16384, 512, 512, 64, 65536, 262144, 32768,
                                      512, 512, 64, 65536, 262144, 32768,
                                      512, 512, 64, 65536, 262144, 32768, 1,
                                      8388608, 8388608};
    static const int sortRole[23]  = {R_ATTB, R_ATTW, R_FB1, R_FB2, R_FBD, R_FW1,
                                      R_FW2, R_FWD, R_MB1, R_MB2, R_MBD, R_MW1,
                                      R_MW2, R_MWD, R_SB1, R_SB2, R_SBD, R_SW1,
                                      R_SW2, R_SWD, -1, R_X, R_Y};
    const void* rp[N_ROLES];
    int rs[N_ROLES];
    for (int i = 0; i < 23 && i < n_in; ++i)
        if (dictRole[i] >= 0) { rp[dictRole[i]] = d_in[i]; rs[dictRole[i]] = in_sizes[i]; }
    {
        bool dictOk = (n_in >= 22);
        for (int i = 0; i < 22 && dictOk; ++i)
            if (in_sizes[i] != dictSizes[i]) dictOk = false;
        if (!dictOk) {
            bool sortOk = (n_in >= 23);
            for (int i = 0; i < 23 && sortOk; ++i)
                if (in_sizes[i] != sortSizes[i]) sortOk = false;
            if (sortOk)
                for (int i = 0; i < 23; ++i)
                    if (sortRole[i] >= 0) { rp[sortRole[i]] = d_in[i]; rs[sortRole[i]] = in_sizes[i]; }
        }
    }

    __bf16* wpack = (__bf16*)d_ws;
    unsigned long long* masks = (unsigned long long*)((char*)d_ws + WS_MASKS);
    int* rrows = (int*)((char*)d_ws + WS_RROWS);
    int* rcnt  = (int*)((char*)d_ws + WS_RCNT);
    int* flags = (int*)((char*)d_ws + WS_FLAGS);

    float* out_f = (float*)d_out;
    float* sub_o = out_f;
    float* mm_o  = out_f + (size_t)BN * 64;
    float* fus_o = out_f + (size_t)2 * BN * 64;

    DetArgs da;
    for (int r = 0; r < N_ROLES; ++r) { da.p[r] = rp[r]; da.n[r] = rs[r]; }
    detect_kernel<<<N_ROLES, 256, 0, stream>>>(da, flags, rcnt);

    PackArgs pa;
    const int prole[10] = {R_SW1, R_SW2, R_SWD, R_MW1, R_MW2, R_MWD,
                           R_FW1, R_FW2, R_FWD, R_ATTW};
    const int Ks[10]   = {128, 512, 512, 128, 512, 512, 128, 512, 512, 128};
    const int Ns[10]   = {512, 512, 64, 512, 512, 64, 512, 512, 64, 128};
    const int offs[10] = {OFF_SW1, OFF_SW2, OFF_SWD, OFF_MW1, OFF_MW2,
                          OFF_MWD, OFF_FW1, OFF_FW2, OFF_FWD, OFF_ATT};
    for (int i = 0; i < 10; ++i) {
        pa.src[i] = rp[prole[i]];
        pa.K[i] = Ks[i];
        pa.N[i] = Ns[i];
        pa.off[i] = offs[i];
        pa.role[i] = prole[i];
    }
    pack_weights<<<dim3(128, 10), 256, 0, stream>>>(pa, wpack, flags);

    sub_mfma<<<BN / 16, 512, 0, stream>>>(
        rp[R_X], wpack, rp[R_SB1], rp[R_SB2], rp[R_SBD], flags,
        sub_o, masks, rrows, rcnt);

    rescue_kernel<<<512, 256, 0, stream>>>(
        rp[R_X], rp[R_SW1], rp[R_SB1], rp[R_SW2], rp[R_SB2], rp[R_SWD], rp[R_SBD],
        flags, rrows, rcnt, sub_o, masks);

    mm_mfma<<<BN / 16, 512, 0, stream>>>(
        masks, rp[R_Y], wpack, rp[R_MB1], rp[R_MB2], rp[R_MBD], flags, mm_o);

    fusion_mfma<<<BN / 16, 512, 0, stream>>>(
        sub_o, mm_o, wpack, rp[R_ATTB], rp[R_FB1], rp[R_FB2], rp[R_FBD],
        flags, fus_o);
}

// Round 2
// 876.768 us; speedup vs baseline: 3.4130x; 1.2847x over previous
//
#include <hip/hip_runtime.h>
#include <math.h>

// ---------------------------------------------------------------------------
// MFMA round. fp32 outputs (validated r6). Per-array dtype detection
// (bf16/fp32/zero). All three MLPs: split-bf16 MFMA (hi/lo planes, 3 terms,
// ~1e-6 abs accuracy). Top-8 correctness vs fp64 reference guaranteed by a
// margin-gated fp64 rescue pass (rows with 8th/9th gap < 1e-4 recomputed).
// This round: M=32 rows/block (2 row-tiles/wave) -> each B-fragment load
// feeds 6 MFMAs (was 3) and per-block weight L2 traffic amortizes over 2x
// rows. LDS re-laid-out unpadded + 4-bit XOR swizzle ((row&15)<<4): 81920 B
// -> exactly 2 blocks/CU; A-reads <=2-way, epilogue writes conflict-free.
// Per-(row,col) accumulation order unchanged -> bitwise-identical outputs.
// ---------------------------------------------------------------------------

typedef __bf16 bf16x8  __attribute__((ext_vector_type(8)));
typedef float  floatx4 __attribute__((ext_vector_type(4)));
#define MFMA(a,b,c) __builtin_amdgcn_mfma_f32_16x16x32_bf16((a),(b),(c),0,0,0)

#define BN 65536
#define MROWS 32
#define MARGIN 1e-4f

// LDS layout (per block, 81920 B total -> 2 blocks/CU on 160 KiB LDS):
//   [0,      8192)  ix hi plane (32 rows x 256 B, swizzled)
//   [8192,  16384)  ix lo plane
//   [16384, 49152)  h  hi plane (32 rows x 1024 B, swizzled)
//   [49152, 81920)  h  lo plane
//   outb (SUB only) aliases [0, 8448): 32 x 66 f32 (ix dead after layer 1)
#define SM_IX0 0
#define SM_IX1 8192
#define SM_H0  16384
#define SM_H1  49152
#define SM_BYTES 81920
#define OBST 66

// packed plane sizes/offsets (bf16 elements); hi at OFF, lo at OFF+SZ
#define SZ_W1 65536
#define SZ_W2 262144
#define SZ_WD 32768
#define SZ_ATT 16384
#define OFF_SW1 0
#define OFF_SW2 (OFF_SW1 + 2*SZ_W1)
#define OFF_SWD (OFF_SW2 + 2*SZ_W2)
#define OFF_MW1 (OFF_SWD + 2*SZ_WD)
#define OFF_MW2 (OFF_MW1 + 2*SZ_W1)
#define OFF_MWD (OFF_MW2 + 2*SZ_W2)
#define OFF_FW1 (OFF_MWD + 2*SZ_WD)
#define OFF_FW2 (OFF_FW1 + 2*SZ_W1)
#define OFF_FWD (OFF_FW2 + 2*SZ_W2)
#define OFF_ATT (OFF_FWD + 2*SZ_WD)

// ws byte offsets (pack ends at ~4.4 MB)
#define WS_MASKS (5u << 20)     // BN * 8 B
#define WS_RROWS (6u << 20)     // up to BN ints
#define WS_RCNT  (7u << 20)     // 1 int
#define WS_FLAGS ((7u << 20) + 256)

enum { R_X = 0, R_Y, R_SW1, R_SB1, R_SW2, R_SB2, R_SWD, R_SBD,
       R_MW1, R_MB1, R_MW2, R_MB2, R_MWD, R_MBD, R_ATTW, R_ATTB,
       R_FW1, R_FB1, R_FW2, R_FB2, R_FWD, R_FBD, N_ROLES };

__device__ __forceinline__ float bf2f(unsigned short u) {
    return __uint_as_float((unsigned)u << 16);
}
// fl: 1=bf16, 0=fp32, 2=zero
__device__ __forceinline__ float loadf(const void* p, size_t i, int fl) {
    return fl == 1 ? bf2f(((const unsigned short*)p)[i])
         : fl == 0 ? ((const float*)p)[i] : 0.f;
}
__device__ __forceinline__ double loadd(const void* p, size_t i, int fl) {
    return fl == 1 ? (double)bf2f(((const unsigned short*)p)[i])
         : fl == 0 ? (double)((const float*)p)[i] : 0.0;
}
// compile-time-flag variant: branch-free loop bodies in the rescue kernel
template<int FL>
__device__ __forceinline__ double ldw(const void* p, size_t i) {
    return FL == 1 ? (double)bf2f(((const unsigned short*)p)[i])
         : FL == 0 ? (double)((const float*)p)[i] : 0.0;
}
struct bf2 { __bf16 hi, lo; };
__device__ __forceinline__ bf2 split2(float v) {
    bf2 r;
    r.hi = (__bf16)v;
    r.lo = (__bf16)(v - (float)r.hi);
    return r;
}
// LDS swizzle: byte offset within a plane; rsB = 256 (ix) or 1024 (h).
// (row&15)<<4 stays below rsB in both cases; preserves 16B alignment.
__device__ __forceinline__ int swz(int row, int colB, int rsB) {
    return (row * rsB + colB) ^ ((row & 15) << 4);
}

// ---------------------------------------------------------------------------
// detect: per-array dtype (1=bf16, 0=fp32, 2=zero). Also zeroes rescue count.
// ---------------------------------------------------------------------------
struct DetArgs { const void* p[N_ROLES]; int n[N_ROLES]; };

__global__ __launch_bounds__(256) void detect_kernel(DetArgs da, int* flags, int* rcnt) {
    const int role = blockIdx.x;
    if (role == 0 && threadIdx.x == 0) *rcnt = 0;
    const unsigned short* u = (const unsigned short*)da.p[role];
    int nsamp = da.n[role] / 2;
    if (nsamp > 4096) nsamp = 4096;
    __shared__ int band, nz;
    if (threadIdx.x == 0) { band = 0; nz = 0; }
    __syncthreads();
    int lb = 0, lnz = 0;
    for (int i = threadIdx.x; i < nsamp; i += 256) {
        const unsigned short v = u[2 * i];
        if (v) {
            ++lnz;
            const int e = (v >> 7) & 0xFF;
            if (e >= 100 && e <= 126) ++lb;
        }
    }
    atomicAdd(&band, lb);
    atomicAdd(&nz, lnz);
    __syncthreads();
    if (threadIdx.x == 0)
        flags[role] = (nz == 0) ? 2 : ((band * 2 > nz) ? 1 : 0);
}

// ---------------------------------------------------------------------------
// pack: [K x N] -> MFMA B-frag hi/lo planes. Frag for tile (kt,nt): lane l,
// j=0..7 holds W[kt*32 + (l>>4)*8 + j][nt*16 + (l&15)].
// ---------------------------------------------------------------------------
struct PackArgs { const void* src[10]; int K[10], N[10], off[10], role[10]; };

__global__ __launch_bounds__(256) void pack_weights(PackArgs pa, __bf16* dst,
                                                    const int* __restrict__ flags) {
    const int m = blockIdx.y;
    const int fl = flags[pa.role[m]];
    const int K = pa.K[m], N = pa.N[m];
    const int KT = K >> 5, NT = N >> 4;
    const int total = KT * NT * 64;
    const int t = blockIdx.x * 256 + threadIdx.x;
    if (t >= total) return;
    const int l = t & 63;
    const int idx = t >> 6;            // nt*KT + kt
    const int kt = idx % KT;
    const int nt = idx / KT;
    const int k0 = kt * 32 + ((l >> 4) << 3);
    const int n  = nt * 16 + (l & 15);
    __bf16* dh = dst + pa.off[m] + (size_t)t * 8;
    __bf16* dl = dh + K * N;
#pragma unroll
    for (int j = 0; j < 8; ++j) {
        const bf2 s = split2(loadf(pa.src[m], (size_t)(k0 + j) * N + n, fl));
        dh[j] = s.hi;
        dl[j] = s.lo;
    }
}

// ---------------------------------------------------------------------------
// Core 3-layer MFMA MLP (32 rows, 512 threads = 8 waves, 2 row-tiles/wave).
// Input from swizzled ix planes in sm; h planes swizzled in sm (in-place L2);
// fp32 out. SUB also mirrors layer-3 output into outb (aliases ix region).
// ---------------------------------------------------------------------------
template <bool SUB>
__device__ __forceinline__ void mlp_core(
    char* __restrict__ sm,
    const __bf16* __restrict__ p1h, const __bf16* __restrict__ p1l,
    const __bf16* __restrict__ p2h, const __bf16* __restrict__ p2l,
    const __bf16* __restrict__ pdh, const __bf16* __restrict__ pdl,
    const void* __restrict__ b1, int fb1,
    const void* __restrict__ b2, int fb2,
    const void* __restrict__ bd, int fbd,
    int r0, float* __restrict__ out)
{
    const int tid = threadIdx.x;
    const int l = tid & 63, w = tid >> 6, l15 = l & 15, q = l >> 4;

    // ---- layer 1: K=128, N=512; wave w owns 64-col slab; 2 row-tiles ----
    floatx4 acc[2][4];
#pragma unroll
    for (int rt = 0; rt < 2; ++rt)
#pragma unroll
        for (int nt = 0; nt < 4; ++nt) acc[rt][nt] = (floatx4)0.0f;
#pragma unroll
    for (int kt = 0; kt < 4; ++kt) {
        const int cB = kt * 64 + q * 16;
        bf16x8 ahi[2], alo[2];
#pragma unroll
        for (int rt = 0; rt < 2; ++rt) {
            const int off = swz(rt * 16 + l15, cB, 256);
            ahi[rt] = *(const bf16x8*)(sm + SM_IX0 + off);
            alo[rt] = *(const bf16x8*)(sm + SM_IX1 + off);
        }
#pragma unroll
        for (int nt = 0; nt < 4; ++nt) {
            const size_t fi = ((((size_t)(w * 4 + nt)) * 4 + kt) * 64 + l) * 8;
            const bf16x8 bhi = *(const bf16x8*)(p1h + fi);
            const bf16x8 blo = *(const bf16x8*)(p1l + fi);
#pragma unroll
            for (int rt = 0; rt < 2; ++rt) {
                acc[rt][nt] = MFMA(alo[rt], bhi, acc[rt][nt]);
                acc[rt][nt] = MFMA(ahi[rt], blo, acc[rt][nt]);
                acc[rt][nt] = MFMA(ahi[rt], bhi, acc[rt][nt]);
            }
        }
    }
#pragma unroll
    for (int nt = 0; nt < 4; ++nt) {
        const int col = w * 64 + nt * 16 + l15;
        const float bias = loadf(b1, col, fb1);
#pragma unroll
        for (int rt = 0; rt < 2; ++rt)
#pragma unroll
            for (int r = 0; r < 4; ++r) {
                const int row = rt * 16 + q * 4 + r;
                float v = acc[rt][nt][r] + bias;
                v = v > 0.f ? v : 0.f;
                const bf2 s = split2(v);
                const int o = swz(row, col * 2, 1024);
                *(__bf16*)(sm + SM_H0 + o) = s.hi;
                *(__bf16*)(sm + SM_H1 + o) = s.lo;
            }
    }
    __syncthreads();

    // ---- layer 2: K=512, in-place ----
    floatx4 acc2[2][4];
#pragma unroll
    for (int rt = 0; rt < 2; ++rt)
#pragma unroll
        for (int nt = 0; nt < 4; ++nt) acc2[rt][nt] = (floatx4)0.0f;
    for (int kt = 0; kt < 16; ++kt) {
        const int cB = kt * 64 + q * 16;
        bf16x8 ahi[2], alo[2];
#pragma unroll
        for (int rt = 0; rt < 2; ++rt) {
            const int off = swz(rt * 16 + l15, cB, 1024);
            ahi[rt] = *(const bf16x8*)(sm + SM_H0 + off);
            alo[rt] = *(const bf16x8*)(sm + SM_H1 + off);
        }
#pragma unroll
        for (int nt = 0; nt < 4; ++nt) {
            const size_t fi = ((((size_t)(w * 4 + nt)) * 16 + kt) * 64 + l) * 8;
            const bf16x8 bhi = *(const bf16x8*)(p2h + fi);
            const bf16x8 blo = *(const bf16x8*)(p2l + fi);
#pragma unroll
            for (int rt = 0; rt < 2; ++rt) {
                acc2[rt][nt] = MFMA(alo[rt], bhi, acc2[rt][nt]);
                acc2[rt][nt] = MFMA(ahi[rt], blo, acc2[rt][nt]);
                acc2[rt][nt] = MFMA(ahi[rt], bhi, acc2[rt][nt]);
            }
        }
    }
    __syncthreads();  // all reads of h done before overwrite
#pragma unroll
    for (int nt = 0; nt < 4; ++nt) {
        const int col = w * 64 + nt * 16 + l15;
        const float bias = loadf(b2, col, fb2);
#pragma unroll
        for (int rt = 0; rt < 2; ++rt)
#pragma unroll
            for (int r = 0; r < 4; ++r) {
                const int row = rt * 16 + q * 4 + r;
                float v = acc2[rt][nt][r] + bias;
                v = v > 0.f ? v : 0.f;
                const bf2 s = split2(v);
                const int o = swz(row, col * 2, 1024);
                *(__bf16*)(sm + SM_H0 + o) = s.hi;
                *(__bf16*)(sm + SM_H1 + o) = s.lo;
            }
    }
    __syncthreads();

    // ---- layer 3: K=512, N=64; all 8 waves: nt=w&3, rt=w>>2 ----
    {
        const int nt3 = w & 3, rt3 = w >> 2;
        floatx4 a3 = (floatx4)0.0f;
        for (int kt = 0; kt < 16; ++kt) {
            const int off = swz(rt3 * 16 + l15, kt * 64 + q * 16, 1024);
            const bf16x8 ahi = *(const bf16x8*)(sm + SM_H0 + off);
            const bf16x8 alo = *(const bf16x8*)(sm + SM_H1 + off);
            const size_t fi = (((size_t)(nt3 * 16 + kt)) * 64 + l) * 8;
            const bf16x8 bhi = *(const bf16x8*)(pdh + fi);
            const bf16x8 blo = *(const bf16x8*)(pdl + fi);
            a3 = MFMA(alo, bhi, a3);
            a3 = MFMA(ahi, blo, a3);
            a3 = MFMA(ahi, bhi, a3);
        }
        const int col = nt3 * 16 + l15;
        const float bias = loadf(bd, col, fbd);
        float* outb = (float*)sm;  // aliases ix region (dead after L1)
#pragma unroll
        for (int r = 0; r < 4; ++r) {
            const int row = rt3 * 16 + q * 4 + r;
            const float v = a3[r] + bias;  // no relu on output layer
            out[(size_t)(r0 + row) * 64 + col] = v;
            if (SUB) outb[row * OBST + col] = v;
        }
    }
    if (SUB) __syncthreads();
}

// ---------------------------------------------------------------------------
// K1: sub MLP + per-row top-8 mask + margin-gated rescue list.
// ---------------------------------------------------------------------------
__global__ __launch_bounds__(512, 4)
void sub_mfma(const void* __restrict__ x, const __bf16* __restrict__ wpack,
              const void* __restrict__ b1, const void* __restrict__ b2,
              const void* __restrict__ bd, const int* __restrict__ flags,
              float* __restrict__ out, unsigned long long* __restrict__ masks,
              int* __restrict__ rrows, int* __restrict__ rcnt)
{
    __shared__ __align__(16) char sm[SM_BYTES];
    const int fx = flags[R_X];
    const int r0 = blockIdx.x * MROWS;

    for (int i = threadIdx.x; i < MROWS * 128; i += 512) {
        const int r = i >> 7, c = i & 127;
        const bf2 s = split2(loadf(x, (size_t)(r0 + r) * 128 + c, fx));
        const int off = swz(r, c * 2, 256);
        *(__bf16*)(sm + SM_IX0 + off) = s.hi;
        *(__bf16*)(sm + SM_IX1 + off) = s.lo;
    }
    __syncthreads();

    mlp_core<true>(sm,
                   wpack + OFF_SW1, wpack + OFF_SW1 + SZ_W1,
                   wpack + OFF_SW2, wpack + OFF_SW2 + SZ_W2,
                   wpack + OFF_SWD, wpack + OFF_SWD + SZ_WD,
                   b1, flags[R_SB1], b2, flags[R_SB2], bd, flags[R_SBD],
                   r0, out);

    // top-9 per row (strict '>' insertion: jax tie rule -> lowest index wins)
    if (threadIdx.x < MROWS) {
        const float* rowp = (const float*)sm + threadIdx.x * OBST;
        float vals[9];
        int idxs[9];
#pragma unroll
        for (int j = 0; j < 9; ++j) { vals[j] = -__builtin_inff(); idxs[j] = 0; }
        for (int i = 0; i < 64; ++i) {
            const float v = rowp[i];
            if (v > vals[8]) {
                int p = 8;
                while (p > 0 && v > vals[p - 1]) {
                    vals[p] = vals[p - 1];
                    idxs[p] = idxs[p - 1];
                    --p;
                }
                vals[p] = v;
                idxs[p] = i;
            }
        }
        unsigned long long m = 0ull;
#pragma unroll
        for (int j = 0; j < 8; ++j) m |= (1ull << idxs[j]);
        masks[r0 + threadIdx.x] = m;
        if (vals[7] - vals[8] < MARGIN) {
            const int slot = atomicAdd(rcnt, 1);
            rrows[slot] = r0 + threadIdx.x;
        }
    }
}

// ---------------------------------------------------------------------------
// K1b: fp64 rescue for marginal rows — recompute sub rows exactly, fix mask
// and out_sub rows. Batched: 16 rows per block-iteration staged in LDS so
// each weight element is loaded once and FMA'd into 16 row-accumulators.
// ---------------------------------------------------------------------------
#define RPB 16
#define XST 130    // xs row stride (128 + 2)
#define HST2 516   // h row stride (512 + 4)

// L1/L2: 256 threads own cols (t, t+256); accumulate 16 rows each.
template<int FL, int K, int S>
__device__ __forceinline__ void r_layer12(const void* __restrict__ W,
                                          const double* __restrict__ in,
                                          double* __restrict__ a0,
                                          double* __restrict__ a1, int t)
{
    for (int k = 0; k < K; ++k) {
        const double w0 = ldw<FL>(W, (size_t)k * 512 + t);
        const double w1 = ldw<FL>(W, (size_t)k * 512 + t + 256);
#pragma unroll
        for (int r = 0; r < RPB; ++r) {
            a0[r] = fma(in[r * S + k], w0, a0[r]);
            a1[r] = fma(in[r * S + k], w1, a1[r]);
        }
    }
}

// L3: thread owns col c = t&63, row-group rg = t>>6 (4 rows).
template<int FL>
__device__ __forceinline__ void r_layer3(const void* __restrict__ W,
                                         const double* __restrict__ h,
                                         int c, int rg, double* __restrict__ a)
{
    for (int k = 0; k < 512; ++k) {
        const double w = ldw<FL>(W, (size_t)k * 64 + c);
#pragma unroll
        for (int j = 0; j < 4; ++j)
            a[j] = fma(h[(rg * 4 + j) * HST2 + k], w, a[j]);
    }
}

#define R_DISPATCH(fl, CALL)                                   \
    do {                                                       \
        if ((fl) == 1)      { CALL(1); }                       \
        else if ((fl) == 0) { CALL(0); }                       \
        else                { CALL(2); }                       \
    } while (0)

__global__ __launch_bounds__(256)
void rescue_kernel(const void* __restrict__ x,
                   const void* __restrict__ W1, const void* __restrict__ b1,
                   const void* __restrict__ W2, const void* __restrict__ b2,
                   const void* __restrict__ Wd, const void* __restrict__ bd,
                   const int* __restrict__ flags,
                   const int* __restrict__ rrows, const int* __restrict__ rcnt,
                   float* __restrict__ out, unsigned long long* __restrict__ masks)
{
    __shared__ double xs[RPB * XST];
    __shared__ double h[RPB * HST2];
    __shared__ double ob[RPB][64];
    __shared__ int rowids[RPB];
    const int fx = flags[R_X], f1 = flags[R_SW1], fb1 = flags[R_SB1],
              f2 = flags[R_SW2], fb2 = flags[R_SB2],
              f3 = flags[R_SWD], fb3 = flags[R_SBD];
    const int t = threadIdx.x;
    const int n = *rcnt;

    for (int g = blockIdx.x; g * RPB < n; g += gridDim.x) {
        const int base = g * RPB;
        int cnt = n - base;
        if (cnt > RPB) cnt = RPB;
        if (t < RPB) rowids[t] = rrows[base + (t < cnt ? t : cnt - 1)];
        __syncthreads();

        // stage inputs (fp64)
        for (int i = t; i < RPB * 128; i += 256) {
            const int r = i >> 7, c = i & 127;
            xs[r * XST + c] = loadd(x, (size_t)rowids[r] * 128 + c, fx);
        }
        __syncthreads();

        // ---- L1: K=128 ----
        {
            double a0[RPB], a1[RPB];
#pragma unroll
            for (int r = 0; r < RPB; ++r) { a0[r] = 0.0; a1[r] = 0.0; }
#define L1_CALL(FL) r_layer12<FL, 128, XST>(W1, xs, a0, a1, t)
            R_DISPATCH(f1, L1_CALL);
#undef L1_CALL
            const double bb0 = loadd(b1, t, fb1), bb1 = loadd(b1, t + 256, fb1);
#pragma unroll
            for (int r = 0; r < RPB; ++r) {
                const double v0 = a0[r] + bb0, v1 = a1[r] + bb1;
                h[r * HST2 + t]       = v0 > 0.0 ? v0 : 0.0;
                h[r * HST2 + t + 256] = v1 > 0.0 ? v1 : 0.0;
            }
        }
        __syncthreads();

        // ---- L2: K=512, in-place (accumulate fully, then overwrite) ----
        {
            double a0[RPB], a1[RPB];
#pragma unroll
            for (int r = 0; r < RPB; ++r) { a0[r] = 0.0; a1[r] = 0.0; }
#define L2_CALL(FL) r_layer12<FL, 512, HST2>(W2, h, a0, a1, t)
            R_DISPATCH(f2, L2_CALL);
#undef L2_CALL
            __syncthreads();  // all reads of h done before overwrite
            const double bb0 = loadd(b2, t, fb2), bb1 = loadd(b2, t + 256, fb2);
#pragma unroll
            for (int r = 0; r < RPB; ++r) {
                const double v0 = a0[r] + bb0, v1 = a1[r] + bb1;
                h[r * HST2 + t]       = v0 > 0.0 ? v0 : 0.0;
                h[r * HST2 + t + 256] = v1 > 0.0 ? v1 : 0.0;
            }
        }
        __syncthreads();

        // ---- L3: K=512, N=64; col c, 4 rows per thread ----
        {
            const int c = t & 63, rg = t >> 6;
            double a[4];
#pragma unroll
            for (int j = 0; j < 4; ++j) a[j] = 0.0;
#define L3_CALL(FL) r_layer3<FL>(Wd, h, c, rg, a)
            R_DISPATCH(f3, L3_CALL);
#undef L3_CALL
            const double bb = loadd(bd, c, fb3);
#pragma unroll
            for (int j = 0; j < 4; ++j) {
                const int r = rg * 4 + j;
                const double v = a[j] + bb;
                ob[r][c] = v;
                if (r < cnt) out[(size_t)rowids[r] * 64 + c] = (float)v;
            }
        }
        __syncthreads();

        // ---- top-8 per valid row (strict '>' insertion, as before) ----
        if (t < cnt) {
            double vals[8];
            int idxs[8];
#pragma unroll
            for (int j = 0; j < 8; ++j) { vals[j] = -1.0e300; idxs[j] = 0; }
            for (int i = 0; i < 64; ++i) {
                const double v = ob[t][i];
                if (v > vals[7]) {
                    int p = 7;
                    while (p > 0 && v > vals[p - 1]) {
                        vals[p] = vals[p - 1];
                        idxs[p] = idxs[p - 1];
                        --p;
                    }
                    vals[p] = v;
                    idxs[p] = i;
                }
            }
            unsigned long long m = 0ull;
#pragma unroll
            for (int j = 0; j < 8; ++j) m |= (1ull << idxs[j]);
            masks[rowids[t]] = m;
        }
        __syncthreads();  // ob/rowids/xs reused next iteration
    }
}

// ---------------------------------------------------------------------------
// K2: mm MLP from masked y.
// ---------------------------------------------------------------------------
__global__ __launch_bounds__(512, 4)
void mm_mfma(const unsigned long long* __restrict__ masks,
             const void* __restrict__ y, const __bf16* __restrict__ wpack,
             const void* __restrict__ b1, const void* __restrict__ b2,
             const void* __restrict__ bd, const int* __restrict__ flags,
             float* __restrict__ out)
{
    __shared__ __align__(16) char sm[SM_BYTES];
    const int fy = flags[R_Y];
    const int r0 = blockIdx.x * MROWS;

    for (int i = threadIdx.x; i < MROWS * 128; i += 512) {
        const int r = i >> 7, c = i & 127;
        const bool keep = (masks[r0 + r] >> (c >> 1)) & 1ull;
        const float v = keep ? loadf(y, (size_t)(r0 + r) * 128 + c, fy) : 0.f;
        const bf2 s = split2(v);
        const int off = swz(r, c * 2, 256);
        *(__bf16*)(sm + SM_IX0 + off) = s.hi;
        *(__bf16*)(sm + SM_IX1 + off) = s.lo;
    }
    __syncthreads();

    mlp_core<false>(sm,
                    wpack + OFF_MW1, wpack + OFF_MW1 + SZ_W1,
                    wpack + OFF_MW2, wpack + OFF_MW2 + SZ_W2,
                    wpack + OFF_MWD, wpack + OFF_MWD + SZ_WD,
                    b1, flags[R_MB1], b2, flags[R_MB2], bd, flags[R_MBD],
                    r0, out);
}

// ---------------------------------------------------------------------------
// K3: cat (fp32 from d_out) -> sigmoid attention gate -> fusion MLP.
// ---------------------------------------------------------------------------
__global__ __launch_bounds__(512, 4)
void fusion_mfma(const float* __restrict__ subf, const float* __restrict__ mmf,
                 const __bf16* __restrict__ wpack,
                 const void* __restrict__ attb,
                 const void* __restrict__ b1, const void* __restrict__ b2,
                 const void* __restrict__ bd, const int* __restrict__ flags,
                 float* __restrict__ out)
{
    __shared__ __align__(16) char sm[SM_BYTES];
    const int tid = threadIdx.x;
    const int l = tid & 63, w = tid >> 6, l15 = l & 15, q = l >> 4;
    const int r0 = blockIdx.x * MROWS;

    for (int i = tid; i < MROWS * 128; i += 512) {
        const int r = i >> 7, c = i & 127;
        const size_t row = (size_t)(r0 + r);
        const float v = (c < 64) ? subf[row * 64 + c] : mmf[row * 64 + (c - 64)];
        const bf2 s = split2(v);
        const int off = swz(r, c * 2, 256);
        *(__bf16*)(sm + SM_IX0 + off) = s.hi;
        *(__bf16*)(sm + SM_IX1 + off) = s.lo;
    }
    __syncthreads();

    // attention: N=128, wave w owns 16-col tile nt=w; 2 row-tiles
    floatx4 aacc[2];
    aacc[0] = (floatx4)0.0f;
    aacc[1] = (floatx4)0.0f;
    const __bf16* path = wpack + OFF_ATT;
    const __bf16* patl = path + SZ_ATT;
#pragma unroll
    for (int kt = 0; kt < 4; ++kt) {
        const int cB = kt * 64 + q * 16;
        bf16x8 ahi[2], alo[2];
#pragma unroll
        for (int rt = 0; rt < 2; ++rt) {
            const int off = swz(rt * 16 + l15, cB, 256);
            ahi[rt] = *(const bf16x8*)(sm + SM_IX0 + off);
            alo[rt] = *(const bf16x8*)(sm + SM_IX1 + off);
        }
        const size_t fi = (((size_t)(w * 4 + kt)) * 64 + l) * 8;
        const bf16x8 bhi = *(const bf16x8*)(path + fi);
        const bf16x8 blo = *(const bf16x8*)(patl + fi);
#pragma unroll
        for (int rt = 0; rt < 2; ++rt) {
            aacc[rt] = MFMA(alo[rt], bhi, aacc[rt]);
            aacc[rt] = MFMA(ahi[rt], blo, aacc[rt]);
            aacc[rt] = MFMA(ahi[rt], bhi, aacc[rt]);
        }
    }
    const int col = w * 16 + l15;
    const float ab = loadf(attb, col, flags[R_ATTB]);
    float gated[2][4];
#pragma unroll
    for (int rt = 0; rt < 2; ++rt)
#pragma unroll
        for (int r = 0; r < 4; ++r) {
            const int rowl = rt * 16 + q * 4 + r;
            const float pre = aacc[rt][r] + ab;
            const float s = 1.f / (1.f + expf(-pre));
            const int off = swz(rowl, col * 2, 256);
            const float catv = (float)*(const __bf16*)(sm + SM_IX0 + off)
                             + (float)*(const __bf16*)(sm + SM_IX1 + off);
            gated[rt][r] = catv * s;
        }
    __syncthreads();  // all attention reads of ix done
#pragma unroll
    for (int rt = 0; rt < 2; ++rt)
#pragma unroll
        for (int r = 0; r < 4; ++r) {
            const int rowl = rt * 16 + q * 4 + r;
            const bf2 s = split2(gated[rt][r]);
            const int off = swz(rowl, col * 2, 256);
            *(__bf16*)(sm + SM_IX0 + off) = s.hi;
            *(__bf16*)(sm + SM_IX1 + off) = s.lo;
        }
    __syncthreads();

    mlp_core<false>(sm,
                    wpack + OFF_FW1, wpack + OFF_FW1 + SZ_W1,
                    wpack + OFF_FW2, wpack + OFF_FW2 + SZ_W2,
                    wpack + OFF_FWD, wpack + OFF_FWD + SZ_WD,
                    b1, flags[R_FB1], b2, flags[R_FB2], bd, flags[R_FBD],
                    r0, out);
}

// ---------------------------------------------------------------------------
extern "C" void kernel_launch(void* const* d_in, const int* in_sizes, int n_in,
                              void* d_out, int out_size, void* d_ws, size_t ws_size,
                              hipStream_t stream)
{
    // ---- resolve input order by size signature (dict order vs sorted) ----
    static const int dictSizes[23] = {8388608, 8388608, 65536, 512, 262144, 512,
                                      32768, 64, 65536, 512, 262144, 512, 32768, 64,
                                      16384, 128, 65536, 512, 262144, 512, 32768, 64, 1};
    static const int dictRole[23]  = {R_X, R_Y, R_SW1, R_SB1, R_SW2, R_SB2, R_SWD, R_SBD,
                                      R_MW1, R_MB1, R_MW2, R_MB2, R_MWD, R_MBD,
                                      R_ATTW, R_ATTB, R_FW1, R_FB1, R_FW2, R_FB2,
                                      R_FWD, R_FBD, -1};
    static const int sortSizes[23] = {128, 16384, 512, 512, 64, 65536, 262144, 32768,
                                      512, 512, 64, 65536, 262144, 32768,
                                      512, 512, 64, 65536, 262144, 32768, 1,
                                      8388608, 8388608};
    static const int sortRole[23]  = {R_ATTB, R_ATTW, R_FB1, R_FB2, R_FBD, R_FW1,
                                      R_FW2, R_FWD, R_MB1, R_MB2, R_MBD, R_MW1,
                                      R_MW2, R_MWD, R_SB1, R_SB2, R_SBD, R_SW1,
                                      R_SW2, R_SWD, -1, R_X, R_Y};
    const void* rp[N_ROLES];
    int rs[N_ROLES];
    for (int i = 0; i < 23 && i < n_in; ++i)
        if (dictRole[i] >= 0) { rp[dictRole[i]] = d_in[i]; rs[dictRole[i]] = in_sizes[i]; }
    {
        bool dictOk = (n_in >= 22);
        for (int i = 0; i < 22 && dictOk; ++i)
            if (in_sizes[i] != dictSizes[i]) dictOk = false;
        if (!dictOk) {
            bool sortOk = (n_in >= 23);
            for (int i = 0; i < 23 && sortOk; ++i)
                if (in_sizes[i] != sortSizes[i]) sortOk = false;
            if (sortOk)
                for (int i = 0; i < 23; ++i)
                    if (sortRole[i] >= 0) { rp[sortRole[i]] = d_in[i]; rs[sortRole[i]] = in_sizes[i]; }
        }
    }

    __bf16* wpack = (__bf16*)d_ws;
    unsigned long long* masks = (unsigned long long*)((char*)d_ws + WS_MASKS);
    int* rrows = (int*)((char*)d_ws + WS_RROWS);
    int* rcnt  = (int*)((char*)d_ws + WS_RCNT);
    int* flags = (int*)((char*)d_ws + WS_FLAGS);

    float* out_f = (float*)d_out;
    float* sub_o = out_f;
    float* mm_o  = out_f + (size_t)BN * 64;
    float* fus_o = out_f + (size_t)2 * BN * 64;

    DetArgs da;
    for (int r = 0; r < N_ROLES; ++r) { da.p[r] = rp[r]; da.n[r] = rs[r]; }
    detect_kernel<<<N_ROLES, 256, 0, stream>>>(da, flags, rcnt);

    PackArgs pa;
    const int prole[10] = {R_SW1, R_SW2, R_SWD, R_MW1, R_MW2, R_MWD,
                           R_FW1, R_FW2, R_FWD, R_ATTW};
    const int Ks[10]   = {128, 512, 512, 128, 512, 512, 128, 512, 512, 128};
    const int Ns[10]   = {512, 512, 64, 512, 512, 64, 512, 512, 64, 128};
    const int offs[10] = {OFF_SW1, OFF_SW2, OFF_SWD, OFF_MW1, OFF_MW2,
                          OFF_MWD, OFF_FW1, OFF_FW2, OFF_FWD, OFF_ATT};
    for (int i = 0; i < 10; ++i) {
        pa.src[i] = rp[prole[i]];
        pa.K[i] = Ks[i];
        pa.N[i] = Ns[i];
        pa.off[i] = offs[i];
        pa.role[i] = prole[i];
    }
    pack_weights<<<dim3(128, 10), 256, 0, stream>>>(pa, wpack, flags);

    sub_mfma<<<BN / MROWS, 512, 0, stream>>>(
        rp[R_X], wpack, rp[R_SB1], rp[R_SB2], rp[R_SBD], flags,
        sub_o, masks, rrows, rcnt);

    rescue_kernel<<<512, 256, 0, stream>>>(
        rp[R_X], rp[R_SW1], rp[R_SB1], rp[R_SW2], rp[R_SB2], rp[R_SWD], rp[R_SBD],
        flags, rrows, rcnt, sub_o, masks);

    mm_mfma<<<BN / MROWS, 512, 0, stream>>>(
        masks, rp[R_Y], wpack, rp[R_MB1], rp[R_MB2], rp[R_MBD], flags, mm_o);

    fusion_mfma<<<BN / MROWS, 512, 0, stream>>>(
        sub_o, mm_o, wpack, rp[R_ATTB], rp[R_FB1], rp[R_FB2], rp[R_FBD],
        flags, fus_o);
}